// Round 4
// baseline (316.710 us; speedup 1.0000x reference)
//
#include <hip/hip_runtime.h>

#define B_   8
#define S_   2048
#define IN_  96
#define H_   256
#define NROW (B_ * S_)          // 16384 rows

typedef float    f32x4 __attribute__((ext_vector_type(4)));
typedef _Float16 f16x8 __attribute__((ext_vector_type(8)));   // 8 fp16 in 4 VGPRs
typedef int      i32x4 __attribute__((ext_vector_type(4)));   // true 16B load

__device__ __forceinline__ unsigned short f2h(float x) {
    return __builtin_bit_cast(unsigned short, (_Float16)x);
}
__device__ __forceinline__ float h2f(unsigned short x) {
    return (float)__builtin_bit_cast(_Float16, x);
}
// LDS-only barrier: P-visibility needs lgkmcnt(0) only; vmem prefetches
// (K next chunk, packed-mask words, V) ride through instead of being
// drained by __syncthreads' vmcnt(0).
__device__ __forceinline__ void lds_barrier() {
    asm volatile("s_waitcnt lgkmcnt(0)\n\ts_barrier" ::: "memory");
}

// ---------------------------------------------------------------------------
// Kernel 0: convert W[96][256] fp32 -> wt[256][96] fp16 (transposed), x3 proj.
// ---------------------------------------------------------------------------
__global__ __launch_bounds__(256) void wconv_kernel(
    const float* __restrict__ Wq, const float* __restrict__ Wk,
    const float* __restrict__ Wv, unsigned short* __restrict__ wt)
{
    const int p  = blockIdx.x >> 3;
    const int h0 = (blockIdx.x & 7) * 32;
    const float* W = (p == 0) ? Wq : (p == 1) ? Wk : Wv;
    unsigned short* dst = wt + (size_t)p * H_ * IN_ + (size_t)h0 * IN_;

    __shared__ unsigned short lds[32][100];
    const int t = threadIdx.x;
    #pragma unroll
    for (int i = 0; i < 12; ++i) {
        int idx = i * 256 + t;
        int f = idx >> 5;
        int hl = idx & 31;
        lds[hl][f] = f2h(W[f * H_ + h0 + hl]);
    }
    __syncthreads();
    #pragma unroll
    for (int j = 0; j < 6; ++j) {
        int e = (j * 256 + t) * 2;
        int hl = e / IN_, f = e % IN_;
        unsigned int pk = (unsigned int)lds[hl][f] |
                          ((unsigned int)lds[hl][f + 1] << 16);
        ((unsigned int*)dst)[j * 256 + t] = pk;
    }
}

// ---------------------------------------------------------------------------
// Kernel 0b: mask bit-pack, line-exact streaming (round-3 version, verified:
// FETCH dropped to compulsory).  Natural-order u32 words.
// ---------------------------------------------------------------------------
__global__ __launch_bounds__(256) void maskpack_kernel(
    const int* __restrict__ mask, unsigned* __restrict__ pm32)
{
    __shared__ unsigned char nib[4][8][64];       // [wave][j][lane]
    const int wave = threadIdx.x >> 6;
    const int lane = threadIdx.x & 63;
    const int wid  = blockIdx.x * 4 + wave;       // 0..8191
    const int r0   = wid * 2;

    const int* m0 = mask + (size_t)r0 * S_ + lane * 4;
    const int* m1 = m0 + S_;
    i32x4 a[8], b[8];
    #pragma unroll
    for (int j = 0; j < 8; ++j)
        a[j] = __builtin_nontemporal_load((const i32x4*)(m0 + j * 256));
    #pragma unroll
    for (int j = 0; j < 8; ++j)
        b[j] = __builtin_nontemporal_load((const i32x4*)(m1 + j * 256));

    #pragma unroll
    for (int j = 0; j < 8; ++j) {
        unsigned n0 = (a[j][0] != 0 ? 1u : 0u) | (a[j][1] != 0 ? 2u : 0u)
                    | (a[j][2] != 0 ? 4u : 0u) | (a[j][3] != 0 ? 8u : 0u);
        unsigned n1 = (b[j][0] != 0 ? 1u : 0u) | (b[j][1] != 0 ? 2u : 0u)
                    | (b[j][2] != 0 ? 4u : 0u) | (b[j][3] != 0 ? 8u : 0u);
        nib[wave][j][lane] = (unsigned char)(n0 | (n1 << 4));
    }
    // same-wave LDS dependency only: no barrier, just drain LDS writes
    asm volatile("s_waitcnt lgkmcnt(0)" ::: "memory");

    unsigned long long v = *(const unsigned long long*)
        &nib[wave][lane >> 3][(lane & 7) * 8];
    unsigned long long x0 = v & 0x0F0F0F0F0F0F0F0FULL;          // row0 nibbles
    unsigned long long x1 = (v >> 4) & 0x0F0F0F0F0F0F0F0FULL;   // row1 nibbles
    x0 = (x0 | (x0 >> 4))  & 0x00FF00FF00FF00FFULL;
    x1 = (x1 | (x1 >> 4))  & 0x00FF00FF00FF00FFULL;
    x0 = (x0 | (x0 >> 8))  & 0x0000FFFF0000FFFFULL;
    x1 = (x1 | (x1 >> 8))  & 0x0000FFFF0000FFFFULL;
    x0 = (x0 | (x0 >> 16)) & 0xFFFFFFFFULL;
    x1 = (x1 | (x1 >> 16)) & 0xFFFFFFFFULL;

    pm32[(size_t)r0 * 64 + lane]       = (unsigned)x0;
    pm32[(size_t)(r0 + 1) * 64 + lane] = (unsigned)x1;
}

// ---------------------------------------------------------------------------
// Kernel 1: QKV projection via fp16 MFMA, writing FRAGMENT-PACKED outputs:
//   pq/pk[t(16-row tile)][s(32-h grp)][lane][8]   (B-/A-frag order, QK^T)
//   pv[bc(64-key chunk)][cid = w*8+ht*2+s2][lane][8]  (B-frag order, PV)
// ---------------------------------------------------------------------------
__global__ __launch_bounds__(256) void proj_kernel3(
    const float* __restrict__ query, const float* __restrict__ key,
    const float* __restrict__ value, const unsigned short* __restrict__ wt,
    const float* __restrict__ bq, const float* __restrict__ bk,
    const float* __restrict__ bv,
    unsigned short* __restrict__ pq, unsigned short* __restrict__ pk,
    unsigned short* __restrict__ pv)
{
    __shared__ unsigned short Xs[3][16][104];     // [p][r][f], pitch 104

    const int t    = threadIdx.x;
    const int lane = t & 63;
    const int wave = t >> 6;
    const int col  = lane & 15;
    const int quad = lane >> 4;
    const int bi   = blockIdx.x;                  // global 16-row tile id
    const int s0   = bi * 16;                     // flat row (b*S + sl)
    const int b    = s0 >> 11;
    const int sl   = s0 & (S_ - 1);

    const float* srcs[3] = { query + (size_t)s0 * IN_,
                             key   + (size_t)s0 * IN_,
                             value + (size_t)s0 * IN_ };
    #pragma unroll
    for (int p = 0; p < 3; ++p) {
        #pragma unroll
        for (int i = 0; i < 2; ++i) {
            int idx = i * 256 + t;                // float4 index, 384 total
            if (idx < 384) {
                f32x4 x = *(const f32x4*)(srcs[p] + idx * 4);
                int r = idx / 24;
                int f = (idx - r * 24) * 4;
                unsigned long long pkk =
                    (unsigned long long)f2h(x[0])
                  | ((unsigned long long)f2h(x[1]) << 16)
                  | ((unsigned long long)f2h(x[2]) << 32)
                  | ((unsigned long long)f2h(x[3]) << 48);
                *(unsigned long long*)&Xs[p][r][f] = pkk;
            }
        }
    }
    __syncthreads();

    const int hc = wave;
    #pragma unroll
    for (int p = 0; p < 3; ++p) {
        const unsigned short* wbase = wt + (size_t)p * H_ * IN_;
        f16x8 wfr[4][3];
        #pragma unroll
        for (int ht = 0; ht < 4; ++ht)
            #pragma unroll
            for (int kc = 0; kc < 3; ++kc)
                wfr[ht][kc] = *(const f16x8*)(wbase
                    + (size_t)(hc * 64 + ht * 16 + col) * IN_ + kc * 32 + quad * 8);
        f16x8 xfr[3];
        #pragma unroll
        for (int kc = 0; kc < 3; ++kc)
            xfr[kc] = *(const f16x8*)&Xs[p][col][kc * 32 + quad * 8];

        f32x4 acc[4];
        #pragma unroll
        for (int ht = 0; ht < 4; ++ht) acc[ht] = (f32x4)(0.0f);
        #pragma unroll
        for (int kc = 0; kc < 3; ++kc)
            #pragma unroll
            for (int ht = 0; ht < 4; ++ht)
                acc[ht] = (p < 2)
                    ? __builtin_amdgcn_mfma_f32_16x16x32_f16(xfr[kc], wfr[ht][kc], acc[ht], 0, 0, 0)
                    : __builtin_amdgcn_mfma_f32_16x16x32_f16(wfr[ht][kc], xfr[kc], acc[ht], 0, 0, 0);

        if (p < 2) {
            unsigned short* dst  = (p == 0) ? pq : pk;
            const float*    bias = (p == 0) ? bq : bk;
            #pragma unroll
            for (int ht = 0; ht < 4; ++ht) {
                float bh = bias[hc * 64 + ht * 16 + col];
                const int s    = hc * 2 + (ht >> 1);
                const int lq   = ((ht & 1) * 2 + (col >> 3)) * 16;
                const int j    = col & 7;
                #pragma unroll
                for (int r = 0; r < 4; ++r)
                    dst[(size_t)(((bi * 8 + s) * 64 + lq + quad * 4 + r)) * 8 + j]
                        = f2h(acc[ht][r] + bh);
            }
        } else {
            const int kl  = (sl & 63) + col;      // key within 64-chunk
            const int c   = sl >> 6;              // chunk within batch
            const int s2  = kl >> 5;
            const int qv  = (kl >> 3) & 3;
            const int jj  = col & 7;
            #pragma unroll
            for (int ht = 0; ht < 4; ++ht) {
                f32x4 b4 = *(const f32x4*)(bv + hc * 64 + ht * 16 + quad * 4);
                #pragma unroll
                for (int r = 0; r < 4; ++r)
                    pv[(size_t)(((b * 32 + c) * 32 + hc * 8 + ht * 2 + s2) * 64
                                + qv * 16 + quad * 4 + r) * 8 + jj]
                        = f2h(acc[ht][r] + b4[r]);
            }
        }
    }
}

// ---------------------------------------------------------------------------
// Kernel 2: flash attention, 4-WAY key-split partials.
//   Round-3 counters: MfmaUtil 16%, VALUBusy 24%, Occupancy 25% -> latency-
//   bound with ~2 effective blocks/CU.  Pipe-busy arithmetic gives a ~20us
//   overlap ceiling; the lever is co-residency: kh in 0..3 (8 chunks/block),
//   grid 2048, VGPR 84 + LDS 25.6KB allow ~6 blocks/CU co-resident.
//   Also: O epilogue transposed through LDS -> coalesced 16B stores (kills
//   the 2x write amplification seen as WRITE_SIZE 33MB vs 16.8 logical).
// ---------------------------------------------------------------------------
__global__ __launch_bounds__(256, 3) void attn_kernel(
    const unsigned short* __restrict__ pq, const unsigned short* __restrict__ pk,
    const unsigned short* __restrict__ pv, const unsigned long long* __restrict__ pm,
    unsigned short* __restrict__ Opart, float* __restrict__ lpart)
{
    __shared__ __align__(16) unsigned short Qs[8192];   // Q frags / O transpose
    __shared__ unsigned short P[2][32][68];       // [buf][q(2 strips)][k], pitch 68
    __shared__ float lsum[4][32];

    const int tid  = threadIdx.x;
    const int wave = tid >> 6;
    const int lane = tid & 63;
    const int col  = lane & 15;
    const int quad = lane >> 4;

    const int b     = blockIdx.x & 7;             // batch == XCD (L2 locality)
    const int strip = (blockIdx.x >> 3) & 63;     // 0..63 (32 rows each)
    const int kh    = blockIdx.x >> 9;            // key quarter: 0..3
    const int q0    = strip << 5;

    // ---- stage Q fragments for both strips into LDS (one-time, 16 KB) ----
    {
        const unsigned short* qsrc = pq + (size_t)(b * 128 + strip * 2) * 4096;
        #pragma unroll
        for (int ph = 0; ph < 4; ++ph) {
            int i = ph * 2048 + tid * 8;
            *(f16x8*)&Qs[i] = *(const f16x8*)(qsrc + i);
        }
    }

    f32x4 O[2][4];                                // [strip][ht] 64-h slice
    #pragma unroll
    for (int st = 0; st < 2; ++st)
        #pragma unroll
        for (int ht = 0; ht < 4; ++ht) O[st][ht] = (f32x4)(0.0f);
    float l0 = 0.0f, l1 = 0.0f;

    const unsigned short* pkb = pk + (size_t)(b * 128) * 4096 + lane * 8;
    const unsigned short* pvb = pv + (size_t)(b * 32) * 32 * 512
                                   + (size_t)wave * 8 * 512 + lane * 8;

    // ---- packed-mask pointers: u32 word per (row, 32-key block) ----
    const unsigned* pm32 = (const unsigned*)pm;
    const int sh = (wave & 1) * 16 + quad * 4;    // bit offset within u32
    const unsigned* mp0 = pm32 + (size_t)(b * S_ + q0 + col) * 64
                        + kh * 16 + (wave >> 1);
    const unsigned* mp1 = mp0 + 16 * 64;          // +16 rows

    // ---- K single buffer: prologue load for chunk 0 (tile kh*32 + wave) ----
    f16x8 kf[8];
    #pragma unroll
    for (int s = 0; s < 8; ++s)
        kf[s] = *(const f16x8*)(pkb + (size_t)(kh * 32 + wave) * 4096 + s * 512);

    unsigned mw0 = mp0[0];
    unsigned mw1 = mp1[0];

    __syncthreads();                              // Q visible (one-time drain)

    #pragma unroll 2
    for (int c = 0; c < 8; ++c) {
        const int pb = c & 1;
        const int cn = (c < 7) ? c + 1 : c;       // clamped prefetch index
        const int gc = kh * 8 + c;                // global 64-key chunk

        // ---- V loads for this chunk (used after the barrier) ----
        const unsigned short* vb = pvb + (size_t)gc * 32 * 512;
        f16x8 vf[4][2];
        #pragma unroll
        for (int ht = 0; ht < 4; ++ht)
            #pragma unroll
            for (int s2 = 0; s2 < 2; ++s2)
                vf[ht][s2] = *(const f16x8*)(vb + (size_t)(ht * 2 + s2) * 512);

        // ---- packed-mask prefetch for next chunk (L2-resident, 4B) ----
        unsigned mn0 = mp0[cn * 2];
        unsigned mn1 = mp1[cn * 2];

        // ---- S^T = K.Q^T for both strips; Q frags streamed from LDS ----
        f32x4 St0 = (f32x4)(0.0f), St1 = (f32x4)(0.0f);
        __builtin_amdgcn_s_setprio(1);
        #pragma unroll
        for (int s = 0; s < 8; ++s) {
            f16x8 q0f = *(const f16x8*)&Qs[s * 512 + lane * 8];
            f16x8 q1f = *(const f16x8*)&Qs[4096 + s * 512 + lane * 8];
            St0 = __builtin_amdgcn_mfma_f32_16x16x32_f16(kf[s], q0f, St0, 0, 0, 0);
            St1 = __builtin_amdgcn_mfma_f32_16x16x32_f16(kf[s], q1f, St1, 0, 0, 0);
        }
        __builtin_amdgcn_s_setprio(0);

        // ---- K reload for next chunk (buffer free after QK; runway =
        //      softmax + barrier + PV, rides through the LDS-only barrier) ----
        {
            const unsigned short* kb = pkb + (size_t)(kh * 32 + cn * 4 + wave) * 4096;
            #pragma unroll
            for (int s = 0; s < 8; ++s)
                kf[s] = *(const f16x8*)(kb + s * 512);
        }

        // ---- fixed-max softmax: p = exp2(s*(1/16)*log2e - 6*log2e) ----
        {
            unsigned bits = mw0 >> sh;
            unsigned long long pk64 = 0;
            #pragma unroll
            for (int r = 0; r < 4; ++r) {
                float e = exp2f(fmaf(St0[r], 0.0901679843f, -8.65617025f));
                float p = ((bits >> r) & 1u) ? e : 0.0f;
                _Float16 ph = (_Float16)p;
                l0 += (float)ph;                  // denom from quantized p
                pk64 |= (unsigned long long)__builtin_bit_cast(unsigned short, ph)
                        << (16 * r);
            }
            *(unsigned long long*)&P[pb][col][wave * 16 + quad * 4] = pk64;
        }
        {
            unsigned bits = mw1 >> sh;
            unsigned long long pk64 = 0;
            #pragma unroll
            for (int r = 0; r < 4; ++r) {
                float e = exp2f(fmaf(St1[r], 0.0901679843f, -8.65617025f));
                float p = ((bits >> r) & 1u) ? e : 0.0f;
                _Float16 ph = (_Float16)p;
                l1 += (float)ph;
                pk64 |= (unsigned long long)__builtin_bit_cast(unsigned short, ph)
                        << (16 * r);
            }
            *(unsigned long long*)&P[pb][16 + col][wave * 16 + quad * 4] = pk64;
        }
        mw0 = mn0; mw1 = mn1;

        lds_barrier();                            // P visible; NO vmem drain

        // ---- O += P . V (64-key chunk, this wave's 64-h slice, 2 strips) ----
        __builtin_amdgcn_s_setprio(1);
        #pragma unroll
        for (int st = 0; st < 2; ++st) {
            #pragma unroll
            for (int s2 = 0; s2 < 2; ++s2) {
                union { unsigned long long u[2]; f16x8 v; } pu;
                const unsigned short* pr = &P[pb][st * 16 + col][s2 * 32 + quad * 8];
                pu.u[0] = *(const unsigned long long*)pr;
                pu.u[1] = *(const unsigned long long*)(pr + 4);
                f16x8 pf = pu.v;
                #pragma unroll
                for (int ht = 0; ht < 4; ++ht)
                    O[st][ht] = __builtin_amdgcn_mfma_f32_16x16x32_f16(pf, vf[ht][s2], O[st][ht], 0, 0, 0);
            }
        }
        __builtin_amdgcn_s_setprio(0);
    }

    // ---- reduce l per strip: quads via shfl, waves via LDS ----
    l0 += __shfl_xor(l0, 16); l0 += __shfl_xor(l0, 32);
    l1 += __shfl_xor(l1, 16); l1 += __shfl_xor(l1, 32);
    if (lane < 16) { lsum[wave][lane] = l0; lsum[wave][16 + lane] = l1; }
    __syncthreads();                              // also: done reading Qs

    if (wave == 0 && lane < 16) {
        #pragma unroll
        for (int st = 0; st < 2; ++st) {
            float lt = lsum[0][st * 16 + lane] + lsum[1][st * 16 + lane]
                     + lsum[2][st * 16 + lane] + lsum[3][st * 16 + lane];
            lpart[(size_t)kh * NROW + b * S_ + q0 + st * 16 + lane] = lt;
        }
    }

    // ---- transpose O through LDS (reuse Qs as OT[32][256]) -> coalesced
    //      16B/lane stores (round-3 scalar stores showed 2x write amp) ----
    unsigned short* OT = Qs;
    #pragma unroll
    for (int st = 0; st < 2; ++st)
        #pragma unroll
        for (int ht = 0; ht < 4; ++ht)
            #pragma unroll
            for (int r = 0; r < 4; ++r)
                OT[(st * 16 + quad * 4 + r) * 256 + wave * 64 + ht * 16 + col]
                    = f2h(O[st][ht][r]);
    __syncthreads();

    unsigned short* ob = Opart + (size_t)kh * NROW * H_
                       + (size_t)(b * S_ + q0) * H_;
    const int rrow = tid >> 3;                    // 0..31
    const int hof  = (tid & 7) * 32;              // 0..224
    #pragma unroll
    for (int j = 0; j < 4; ++j)
        *(f16x8*)(ob + (size_t)rrow * H_ + hof + j * 8)
            = *(const f16x8*)(OT + rrow * 256 + hof + j * 8);
}

// ---------------------------------------------------------------------------
// Kernel 3: merge the 4 key-quarter partials + normalize + LayerNorm.
// One WAVE per row: 8B/lane fp16 loads, float4 stores, full-wave shfl reduce.
// ---------------------------------------------------------------------------
__global__ __launch_bounds__(256) void merge_ln_kernel(
    const unsigned short* __restrict__ Opart, const float* __restrict__ lpart,
    const float* __restrict__ gamma, const float* __restrict__ beta,
    float* __restrict__ out)
{
    const int row  = blockIdx.x * 4 + (threadIdx.x >> 6);
    const int lane = threadIdx.x & 63;

    float linv = 1.0f / (lpart[row] + lpart[NROW + row]
                       + lpart[2 * NROW + row] + lpart[3 * NROW + row]);

    const unsigned short* o0 = Opart + (size_t)row * H_ + lane * 4;
    unsigned long long a0 = *(const unsigned long long*)o0;
    unsigned long long a1 = *(const unsigned long long*)(o0 + (size_t)NROW * H_);
    unsigned long long a2 = *(const unsigned long long*)(o0 + (size_t)2 * NROW * H_);
    unsigned long long a3 = *(const unsigned long long*)(o0 + (size_t)3 * NROW * H_);

    float vals[4];
    float sum = 0.0f;
    #pragma unroll
    for (int j = 0; j < 4; ++j) {
        vals[j] = (h2f((unsigned short)(a0 >> (16 * j)))
                 + h2f((unsigned short)(a1 >> (16 * j)))
                 + h2f((unsigned short)(a2 >> (16 * j)))
                 + h2f((unsigned short)(a3 >> (16 * j)))) * linv;
        sum += vals[j];
    }
    sum += __shfl_xor(sum, 1);  sum += __shfl_xor(sum, 2);
    sum += __shfl_xor(sum, 4);  sum += __shfl_xor(sum, 8);
    sum += __shfl_xor(sum, 16); sum += __shfl_xor(sum, 32);
    float mu = sum * (1.0f / H_);

    float sq = 0.0f;
    #pragma unroll
    for (int j = 0; j < 4; ++j) {
        float d = vals[j] - mu;
        sq += d * d;
    }
    sq += __shfl_xor(sq, 1);  sq += __shfl_xor(sq, 2);
    sq += __shfl_xor(sq, 4);  sq += __shfl_xor(sq, 8);
    sq += __shfl_xor(sq, 16); sq += __shfl_xor(sq, 32);
    float rstd = rsqrtf(sq * (1.0f / H_) + 1e-6f);

    f32x4 g  = *(const f32x4*)(gamma + lane * 4);
    f32x4 be = *(const f32x4*)(beta  + lane * 4);
    f32x4 o;
    #pragma unroll
    for (int j = 0; j < 4; ++j)
        o[j] = (vals[j] - mu) * rstd * g[j] + be[j];
    *(f32x4*)(out + (size_t)row * H_ + lane * 4) = o;
}

// ---------------------------------------------------------------------------
extern "C" void kernel_launch(void* const* d_in, const int* in_sizes, int n_in,
                              void* d_out, int out_size, void* d_ws, size_t ws_size,
                              hipStream_t stream)
{
    const float* query = (const float*)d_in[0];
    const float* key   = (const float*)d_in[1];
    const float* value = (const float*)d_in[2];
    const int*   mask  = (const int*)d_in[3];
    const float* Wq = (const float*)d_in[4];
    const float* bq = (const float*)d_in[5];
    const float* Wk = (const float*)d_in[6];
    const float* bk = (const float*)d_in[7];
    const float* Wv = (const float*)d_in[8];
    const float* bv = (const float*)d_in[9];
    const float* gamma = (const float*)d_in[10];
    const float* beta  = (const float*)d_in[11];
    float* out = (float*)d_out;

    const size_t NQK = (size_t)B_ * S_ * H_;             // 4.19M elem each
    unsigned short* pq = (unsigned short*)d_ws;          // frag-packed Q (fp16)
    unsigned short* pk = pq + NQK;                       // frag-packed K (fp16)
    unsigned short* pv = pk + NQK;                       // frag-packed V (fp16)
    unsigned short* wt = pv + NQK;                       // [3][256][96] fp16
    unsigned short* Op = wt + (size_t)3 * H_ * IN_;      // [4][NROW][256] fp16
    float*          lp = (float*)(Op + (size_t)4 * NROW * H_);  // [4][NROW] fp32
    unsigned long long* pm = (unsigned long long*)(lp + 4 * NROW); // [NROW][32] bits

    wconv_kernel<<<24, 256, 0, stream>>>(Wq, Wk, Wv, wt);
    maskpack_kernel<<<2048, 256, 0, stream>>>(mask, (unsigned*)pm);
    proj_kernel3<<<B_ * S_ / 16, 256, 0, stream>>>(query, key, value, wt,
                                                   bq, bk, bv, pq, pk, pv);
    attn_kernel<<<B_ * S_ / 32 * 4, 256, 0, stream>>>(pq, pk, pv, pm, Op, lp);
    merge_ln_kernel<<<NROW / 4, 256, 0, stream>>>(Op, lp, gamma, beta, out);
}

// Round 5
// 306.954 us; speedup vs baseline: 1.0318x; 1.0318x over previous
//
#include <hip/hip_runtime.h>

#define B_   8
#define S_   2048
#define IN_  96
#define H_   256
#define NROW (B_ * S_)          // 16384 rows

typedef float    f32x4 __attribute__((ext_vector_type(4)));
typedef _Float16 f16x8 __attribute__((ext_vector_type(8)));   // 8 fp16 in 4 VGPRs
typedef int      i32x4 __attribute__((ext_vector_type(4)));   // true 16B load

__device__ __forceinline__ unsigned short f2h(float x) {
    return __builtin_bit_cast(unsigned short, (_Float16)x);
}
__device__ __forceinline__ float h2f(unsigned short x) {
    return (float)__builtin_bit_cast(_Float16, x);
}
// LDS-only barrier: P-visibility needs lgkmcnt(0) only; vmem prefetches
// (K next chunk, packed-mask words, V) ride through instead of being
// drained by __syncthreads' vmcnt(0).
__device__ __forceinline__ void lds_barrier() {
    asm volatile("s_waitcnt lgkmcnt(0)\n\ts_barrier" ::: "memory");
}

// ---------------------------------------------------------------------------
// Kernel 0: convert W[96][256] fp32 -> wt[256][96] fp16 (transposed), x3 proj.
// ---------------------------------------------------------------------------
__global__ __launch_bounds__(256) void wconv_kernel(
    const float* __restrict__ Wq, const float* __restrict__ Wk,
    const float* __restrict__ Wv, unsigned short* __restrict__ wt)
{
    const int p  = blockIdx.x >> 3;
    const int h0 = (blockIdx.x & 7) * 32;
    const float* W = (p == 0) ? Wq : (p == 1) ? Wk : Wv;
    unsigned short* dst = wt + (size_t)p * H_ * IN_ + (size_t)h0 * IN_;

    __shared__ unsigned short lds[32][100];
    const int t = threadIdx.x;
    #pragma unroll
    for (int i = 0; i < 12; ++i) {
        int idx = i * 256 + t;
        int f = idx >> 5;
        int hl = idx & 31;
        lds[hl][f] = f2h(W[f * H_ + h0 + hl]);
    }
    __syncthreads();
    #pragma unroll
    for (int j = 0; j < 6; ++j) {
        int e = (j * 256 + t) * 2;
        int hl = e / IN_, f = e % IN_;
        unsigned int pk = (unsigned int)lds[hl][f] |
                          ((unsigned int)lds[hl][f + 1] << 16);
        ((unsigned int*)dst)[j * 256 + t] = pk;
    }
}

// ---------------------------------------------------------------------------
// Kernel 0b: mask bit-pack, line-exact streaming (verified: FETCH at
// compulsory).  Natural-order u32 words.
// ---------------------------------------------------------------------------
__global__ __launch_bounds__(256) void maskpack_kernel(
    const int* __restrict__ mask, unsigned* __restrict__ pm32)
{
    __shared__ unsigned char nib[4][8][64];       // [wave][j][lane]
    const int wave = threadIdx.x >> 6;
    const int lane = threadIdx.x & 63;
    const int wid  = blockIdx.x * 4 + wave;       // 0..8191
    const int r0   = wid * 2;

    const int* m0 = mask + (size_t)r0 * S_ + lane * 4;
    const int* m1 = m0 + S_;
    i32x4 a[8], b[8];
    #pragma unroll
    for (int j = 0; j < 8; ++j)
        a[j] = __builtin_nontemporal_load((const i32x4*)(m0 + j * 256));
    #pragma unroll
    for (int j = 0; j < 8; ++j)
        b[j] = __builtin_nontemporal_load((const i32x4*)(m1 + j * 256));

    #pragma unroll
    for (int j = 0; j < 8; ++j) {
        unsigned n0 = (a[j][0] != 0 ? 1u : 0u) | (a[j][1] != 0 ? 2u : 0u)
                    | (a[j][2] != 0 ? 4u : 0u) | (a[j][3] != 0 ? 8u : 0u);
        unsigned n1 = (b[j][0] != 0 ? 1u : 0u) | (b[j][1] != 0 ? 2u : 0u)
                    | (b[j][2] != 0 ? 4u : 0u) | (b[j][3] != 0 ? 8u : 0u);
        nib[wave][j][lane] = (unsigned char)(n0 | (n1 << 4));
    }
    // same-wave LDS dependency only: no barrier, just drain LDS writes
    asm volatile("s_waitcnt lgkmcnt(0)" ::: "memory");

    unsigned long long v = *(const unsigned long long*)
        &nib[wave][lane >> 3][(lane & 7) * 8];
    unsigned long long x0 = v & 0x0F0F0F0F0F0F0F0FULL;          // row0 nibbles
    unsigned long long x1 = (v >> 4) & 0x0F0F0F0F0F0F0F0FULL;   // row1 nibbles
    x0 = (x0 | (x0 >> 4))  & 0x00FF00FF00FF00FFULL;
    x1 = (x1 | (x1 >> 4))  & 0x00FF00FF00FF00FFULL;
    x0 = (x0 | (x0 >> 8))  & 0x0000FFFF0000FFFFULL;
    x1 = (x1 | (x1 >> 8))  & 0x0000FFFF0000FFFFULL;
    x0 = (x0 | (x0 >> 16)) & 0xFFFFFFFFULL;
    x1 = (x1 | (x1 >> 16)) & 0xFFFFFFFFULL;

    pm32[(size_t)r0 * 64 + lane]       = (unsigned)x0;
    pm32[(size_t)(r0 + 1) * 64 + lane] = (unsigned)x1;
}

// ---------------------------------------------------------------------------
// Kernel 1: QKV projection via fp16 MFMA, writing FRAGMENT-PACKED outputs:
//   pq/pk[t(16-row tile)][s(32-h grp)][lane][8]   (B-/A-frag order, QK^T)
//   pv[bc(64-key chunk)][cid = w*8+ht*2+s2][lane][8]  (B-frag order, PV)
// ---------------------------------------------------------------------------
__global__ __launch_bounds__(256) void proj_kernel3(
    const float* __restrict__ query, const float* __restrict__ key,
    const float* __restrict__ value, const unsigned short* __restrict__ wt,
    const float* __restrict__ bq, const float* __restrict__ bk,
    const float* __restrict__ bv,
    unsigned short* __restrict__ pq, unsigned short* __restrict__ pk,
    unsigned short* __restrict__ pv)
{
    __shared__ unsigned short Xs[3][16][104];     // [p][r][f], pitch 104

    const int t    = threadIdx.x;
    const int lane = t & 63;
    const int wave = t >> 6;
    const int col  = lane & 15;
    const int quad = lane >> 4;
    const int bi   = blockIdx.x;                  // global 16-row tile id
    const int s0   = bi * 16;                     // flat row (b*S + sl)
    const int b    = s0 >> 11;
    const int sl   = s0 & (S_ - 1);

    const float* srcs[3] = { query + (size_t)s0 * IN_,
                             key   + (size_t)s0 * IN_,
                             value + (size_t)s0 * IN_ };
    #pragma unroll
    for (int p = 0; p < 3; ++p) {
        #pragma unroll
        for (int i = 0; i < 2; ++i) {
            int idx = i * 256 + t;                // float4 index, 384 total
            if (idx < 384) {
                f32x4 x = *(const f32x4*)(srcs[p] + idx * 4);
                int r = idx / 24;
                int f = (idx - r * 24) * 4;
                unsigned long long pkk =
                    (unsigned long long)f2h(x[0])
                  | ((unsigned long long)f2h(x[1]) << 16)
                  | ((unsigned long long)f2h(x[2]) << 32)
                  | ((unsigned long long)f2h(x[3]) << 48);
                *(unsigned long long*)&Xs[p][r][f] = pkk;
            }
        }
    }
    __syncthreads();

    const int hc = wave;
    #pragma unroll
    for (int p = 0; p < 3; ++p) {
        const unsigned short* wbase = wt + (size_t)p * H_ * IN_;
        f16x8 wfr[4][3];
        #pragma unroll
        for (int ht = 0; ht < 4; ++ht)
            #pragma unroll
            for (int kc = 0; kc < 3; ++kc)
                wfr[ht][kc] = *(const f16x8*)(wbase
                    + (size_t)(hc * 64 + ht * 16 + col) * IN_ + kc * 32 + quad * 8);
        f16x8 xfr[3];
        #pragma unroll
        for (int kc = 0; kc < 3; ++kc)
            xfr[kc] = *(const f16x8*)&Xs[p][col][kc * 32 + quad * 8];

        f32x4 acc[4];
        #pragma unroll
        for (int ht = 0; ht < 4; ++ht) acc[ht] = (f32x4)(0.0f);
        #pragma unroll
        for (int kc = 0; kc < 3; ++kc)
            #pragma unroll
            for (int ht = 0; ht < 4; ++ht)
                acc[ht] = (p < 2)
                    ? __builtin_amdgcn_mfma_f32_16x16x32_f16(xfr[kc], wfr[ht][kc], acc[ht], 0, 0, 0)
                    : __builtin_amdgcn_mfma_f32_16x16x32_f16(wfr[ht][kc], xfr[kc], acc[ht], 0, 0, 0);

        if (p < 2) {
            unsigned short* dst  = (p == 0) ? pq : pk;
            const float*    bias = (p == 0) ? bq : bk;
            #pragma unroll
            for (int ht = 0; ht < 4; ++ht) {
                float bh = bias[hc * 64 + ht * 16 + col];
                const int s    = hc * 2 + (ht >> 1);
                const int lq   = ((ht & 1) * 2 + (col >> 3)) * 16;
                const int j    = col & 7;
                #pragma unroll
                for (int r = 0; r < 4; ++r)
                    dst[(size_t)(((bi * 8 + s) * 64 + lq + quad * 4 + r)) * 8 + j]
                        = f2h(acc[ht][r] + bh);
            }
        } else {
            const int kl  = (sl & 63) + col;      // key within 64-chunk
            const int c   = sl >> 6;              // chunk within batch
            const int s2  = kl >> 5;
            const int qv  = (kl >> 3) & 3;
            const int jj  = col & 7;
            #pragma unroll
            for (int ht = 0; ht < 4; ++ht) {
                f32x4 b4 = *(const f32x4*)(bv + hc * 64 + ht * 16 + quad * 4);
                #pragma unroll
                for (int r = 0; r < 4; ++r)
                    pv[(size_t)(((b * 32 + c) * 32 + hc * 8 + ht * 2 + s2) * 64
                                + qv * 16 + quad * 4 + r) * 8 + jj]
                        = f2h(acc[ht][r] + b4[r]);
            }
        }
    }
}

// ---------------------------------------------------------------------------
// Kernel 2: flash attention, 4-way key split, ROTATED software pipeline.
//   Round-4 post-mortem: per-chunk wall ~3200cyc vs ~1285 busy; the stall is
//   the ZERO-SLACK inter-wave dependency Pwrite(c) -> barrier -> PV(c).
//   Rotation: iter i does { V(i) loads | QK(i+1) | K(i+2) issue | sm(i+1) ->
//   Pwrite(i+1, buf^1) | PV(i, buf) | lds_barrier }.  P producer->consumer
//   distance becomes a full iteration (~1500cyc slack); barriers separate
//   independent work.  Epilogue: 32-lane-contiguous row stores (round-4
//   WRITE_SIZE showed 2x amplification from 64B-stride lanes).
// ---------------------------------------------------------------------------
__global__ __launch_bounds__(256, 3) void attn_kernel(
    const unsigned short* __restrict__ pq, const unsigned short* __restrict__ pk,
    const unsigned short* __restrict__ pv, const unsigned long long* __restrict__ pm,
    unsigned short* __restrict__ Opart, float* __restrict__ lpart)
{
    __shared__ __align__(16) unsigned short Qs[8192];   // Q frags / O transpose
    __shared__ unsigned short P[2][32][68];       // [buf][q(2 strips)][k], pitch 68
    __shared__ float lsum[4][32];

    const int tid  = threadIdx.x;
    const int wave = tid >> 6;
    const int lane = tid & 63;
    const int col  = lane & 15;
    const int quad = lane >> 4;

    const int b     = blockIdx.x & 7;             // batch == XCD (L2 locality)
    const int strip = (blockIdx.x >> 3) & 63;     // 0..63 (32 rows each)
    const int kh    = blockIdx.x >> 9;            // key quarter: 0..3
    const int q0    = strip << 5;

    // ---- stage Q fragments for both strips into LDS (one-time, 16 KB) ----
    {
        const unsigned short* qsrc = pq + (size_t)(b * 128 + strip * 2) * 4096;
        #pragma unroll
        for (int ph = 0; ph < 4; ++ph) {
            int i = ph * 2048 + tid * 8;
            *(f16x8*)&Qs[i] = *(const f16x8*)(qsrc + i);
        }
    }

    f32x4 O[2][4];                                // [strip][ht] 64-h slice
    #pragma unroll
    for (int st = 0; st < 2; ++st)
        #pragma unroll
        for (int ht = 0; ht < 4; ++ht) O[st][ht] = (f32x4)(0.0f);
    float l0 = 0.0f, l1 = 0.0f;

    const unsigned short* pkb = pk + (size_t)(b * 128) * 4096 + lane * 8;
    const unsigned short* pvb = pv + (size_t)(b * 32) * 32 * 512
                                   + (size_t)wave * 8 * 512 + lane * 8;

    // ---- packed-mask pointers: u32 word per (row, 32-key block) ----
    const unsigned* pm32 = (const unsigned*)pm;
    const int sh = (wave & 1) * 16 + quad * 4;    // bit offset within u32
    const unsigned* mp0 = pm32 + (size_t)(b * S_ + q0 + col) * 64
                        + kh * 16 + (wave >> 1);
    const unsigned* mp1 = mp0 + 16 * 64;          // +16 rows

    // ---- K single buffer: load K(0) (tile kh*32 + wave) ----
    f16x8 kf[8];
    #pragma unroll
    for (int s = 0; s < 8; ++s)
        kf[s] = *(const f16x8*)(pkb + (size_t)(kh * 32 + wave) * 4096 + s * 512);

    unsigned mc0 = mp0[0];                        // mask(0)
    unsigned mc1 = mp1[0];

    lds_barrier();                                // Q visible (no vmem drain)

    // ---- pipeline prologue: QK(0) -> sm(0) -> Pwrite(0, buf0) ----
    {
        f32x4 St0 = (f32x4)(0.0f), St1 = (f32x4)(0.0f);
        __builtin_amdgcn_s_setprio(1);
        #pragma unroll
        for (int s = 0; s < 8; ++s) {
            f16x8 q0f = *(const f16x8*)&Qs[s * 512 + lane * 8];
            f16x8 q1f = *(const f16x8*)&Qs[4096 + s * 512 + lane * 8];
            St0 = __builtin_amdgcn_mfma_f32_16x16x32_f16(kf[s], q0f, St0, 0, 0, 0);
            St1 = __builtin_amdgcn_mfma_f32_16x16x32_f16(kf[s], q1f, St1, 0, 0, 0);
        }
        __builtin_amdgcn_s_setprio(0);

        // K(1) reload
        {
            const unsigned short* kb = pkb + (size_t)(kh * 32 + 4 + wave) * 4096;
            #pragma unroll
            for (int s = 0; s < 8; ++s)
                kf[s] = *(const f16x8*)(kb + s * 512);
        }
        unsigned mn0 = mp0[2];                    // mask(1)
        unsigned mn1 = mp1[2];

        {
            unsigned bits = mc0 >> sh;
            unsigned long long pk64 = 0;
            #pragma unroll
            for (int r = 0; r < 4; ++r) {
                float e = exp2f(fmaf(St0[r], 0.0901679843f, -8.65617025f));
                float p = ((bits >> r) & 1u) ? e : 0.0f;
                _Float16 ph = (_Float16)p;
                l0 += (float)ph;
                pk64 |= (unsigned long long)__builtin_bit_cast(unsigned short, ph)
                        << (16 * r);
            }
            *(unsigned long long*)&P[0][col][wave * 16 + quad * 4] = pk64;
        }
        {
            unsigned bits = mc1 >> sh;
            unsigned long long pk64 = 0;
            #pragma unroll
            for (int r = 0; r < 4; ++r) {
                float e = exp2f(fmaf(St1[r], 0.0901679843f, -8.65617025f));
                float p = ((bits >> r) & 1u) ? e : 0.0f;
                _Float16 ph = (_Float16)p;
                l1 += (float)ph;
                pk64 |= (unsigned long long)__builtin_bit_cast(unsigned short, ph)
                        << (16 * r);
            }
            *(unsigned long long*)&P[0][16 + col][wave * 16 + quad * 4] = pk64;
        }
        mc0 = mn0; mc1 = mn1;

        lds_barrier();                            // P(0) visible
    }

    // ---- main loop: iter i computes QK(i+1) and PV(i) ----
    #pragma unroll 2
    for (int i = 0; i < 7; ++i) {
        const int pb  = i & 1;
        const int cn2 = (i < 5) ? i + 2 : 7;      // K/mask prefetch, clamped
        const int gc  = kh * 8 + i;               // global 64-key chunk for PV

        // ---- V(i) loads (consumed at PV below, ~700cyc runway) ----
        const unsigned short* vb = pvb + (size_t)gc * 32 * 512;
        f16x8 vf[4][2];
        #pragma unroll
        for (int ht = 0; ht < 4; ++ht)
            #pragma unroll
            for (int s2 = 0; s2 < 2; ++s2)
                vf[ht][s2] = *(const f16x8*)(vb + (size_t)(ht * 2 + s2) * 512);

        // ---- QK(i+1): kf holds K(i+1) ----
        f32x4 St0 = (f32x4)(0.0f), St1 = (f32x4)(0.0f);
        __builtin_amdgcn_s_setprio(1);
        #pragma unroll
        for (int s = 0; s < 8; ++s) {
            f16x8 q0f = *(const f16x8*)&Qs[s * 512 + lane * 8];
            f16x8 q1f = *(const f16x8*)&Qs[4096 + s * 512 + lane * 8];
            St0 = __builtin_amdgcn_mfma_f32_16x16x32_f16(kf[s], q0f, St0, 0, 0, 0);
            St1 = __builtin_amdgcn_mfma_f32_16x16x32_f16(kf[s], q1f, St1, 0, 0, 0);
        }
        __builtin_amdgcn_s_setprio(0);

        // ---- K(i+2) reload (consumed next iter; rides through barrier) ----
        {
            const unsigned short* kb = pkb + (size_t)(kh * 32 + cn2 * 4 + wave) * 4096;
            #pragma unroll
            for (int s = 0; s < 8; ++s)
                kf[s] = *(const f16x8*)(kb + s * 512);
        }
        // ---- mask(i+2) prefetch (L2-resident, 4B) ----
        unsigned mn0 = mp0[cn2 * 2];
        unsigned mn1 = mp1[cn2 * 2];

        // ---- sm(i+1) -> Pwrite into buf pb^1 ----
        {
            unsigned bits = mc0 >> sh;
            unsigned long long pk64 = 0;
            #pragma unroll
            for (int r = 0; r < 4; ++r) {
                float e = exp2f(fmaf(St0[r], 0.0901679843f, -8.65617025f));
                float p = ((bits >> r) & 1u) ? e : 0.0f;
                _Float16 ph = (_Float16)p;
                l0 += (float)ph;
                pk64 |= (unsigned long long)__builtin_bit_cast(unsigned short, ph)
                        << (16 * r);
            }
            *(unsigned long long*)&P[pb ^ 1][col][wave * 16 + quad * 4] = pk64;
        }
        {
            unsigned bits = mc1 >> sh;
            unsigned long long pk64 = 0;
            #pragma unroll
            for (int r = 0; r < 4; ++r) {
                float e = exp2f(fmaf(St1[r], 0.0901679843f, -8.65617025f));
                float p = ((bits >> r) & 1u) ? e : 0.0f;
                _Float16 ph = (_Float16)p;
                l1 += (float)ph;
                pk64 |= (unsigned long long)__builtin_bit_cast(unsigned short, ph)
                        << (16 * r);
            }
            *(unsigned long long*)&P[pb ^ 1][16 + col][wave * 16 + quad * 4] = pk64;
        }
        mc0 = mn0; mc1 = mn1;

        // ---- PV(i) from P[pb] (visible since end of previous iter) ----
        __builtin_amdgcn_s_setprio(1);
        #pragma unroll
        for (int st = 0; st < 2; ++st) {
            #pragma unroll
            for (int s2 = 0; s2 < 2; ++s2) {
                union { unsigned long long u[2]; f16x8 v; } pu;
                const unsigned short* pr = &P[pb][st * 16 + col][s2 * 32 + quad * 8];
                pu.u[0] = *(const unsigned long long*)pr;
                pu.u[1] = *(const unsigned long long*)(pr + 4);
                f16x8 pf = pu.v;
                #pragma unroll
                for (int ht = 0; ht < 4; ++ht)
                    O[st][ht] = __builtin_amdgcn_mfma_f32_16x16x32_f16(pf, vf[ht][s2], O[st][ht], 0, 0, 0);
            }
        }
        __builtin_amdgcn_s_setprio(0);

        lds_barrier();                            // P(i+1) visible
    }

    // ---- pipeline epilogue: PV(7) from P[1] ----
    {
        const unsigned short* vb = pvb + (size_t)(kh * 8 + 7) * 32 * 512;
        f16x8 vf[4][2];
        #pragma unroll
        for (int ht = 0; ht < 4; ++ht)
            #pragma unroll
            for (int s2 = 0; s2 < 2; ++s2)
                vf[ht][s2] = *(const f16x8*)(vb + (size_t)(ht * 2 + s2) * 512);
        __builtin_amdgcn_s_setprio(1);
        #pragma unroll
        for (int st = 0; st < 2; ++st) {
            #pragma unroll
            for (int s2 = 0; s2 < 2; ++s2) {
                union { unsigned long long u[2]; f16x8 v; } pu;
                const unsigned short* pr = &P[1][st * 16 + col][s2 * 32 + quad * 8];
                pu.u[0] = *(const unsigned long long*)pr;
                pu.u[1] = *(const unsigned long long*)(pr + 4);
                f16x8 pf = pu.v;
                #pragma unroll
                for (int ht = 0; ht < 4; ++ht)
                    O[st][ht] = __builtin_amdgcn_mfma_f32_16x16x32_f16(pf, vf[ht][s2], O[st][ht], 0, 0, 0);
            }
        }
        __builtin_amdgcn_s_setprio(0);
    }

    // ---- reduce l per strip: quads via shfl, waves via LDS ----
    l0 += __shfl_xor(l0, 16); l0 += __shfl_xor(l0, 32);
    l1 += __shfl_xor(l1, 16); l1 += __shfl_xor(l1, 32);
    if (lane < 16) { lsum[wave][lane] = l0; lsum[wave][16 + lane] = l1; }
    __syncthreads();                              // also: done reading Qs/P

    if (wave == 0 && lane < 16) {
        #pragma unroll
        for (int st = 0; st < 2; ++st) {
            float lt = lsum[0][st * 16 + lane] + lsum[1][st * 16 + lane]
                     + lsum[2][st * 16 + lane] + lsum[3][st * 16 + lane];
            lpart[(size_t)kh * NROW + b * S_ + q0 + st * 16 + lane] = lt;
        }
    }

    // ---- transpose O through LDS (reuse Qs as OT[32][256]) ----
    unsigned short* OT = Qs;
    #pragma unroll
    for (int st = 0; st < 2; ++st)
        #pragma unroll
        for (int ht = 0; ht < 4; ++ht)
            #pragma unroll
            for (int r = 0; r < 4; ++r)
                OT[(st * 16 + quad * 4 + r) * 256 + wave * 64 + ht * 16 + col]
                    = f2h(O[st][ht][r]);
    __syncthreads();

    // ---- fully-contiguous stores: 32 lanes = one 512B row per instr ----
    unsigned short* ob = Opart + (size_t)kh * NROW * H_
                       + (size_t)(b * S_ + q0) * H_;
    const int r8 = tid >> 5;                      // 0..7
    const int c8 = (tid & 31) * 8;                // element offset in row
    #pragma unroll
    for (int j = 0; j < 4; ++j) {
        const int row = j * 8 + r8;
        *(f16x8*)(ob + (size_t)row * H_ + c8)
            = *(const f16x8*)(OT + row * 256 + c8);
    }
}

// ---------------------------------------------------------------------------
// Kernel 3: merge the 4 key-quarter partials + normalize + LayerNorm.
// One WAVE per row: 8B/lane fp16 loads, float4 stores, full-wave shfl reduce.
// ---------------------------------------------------------------------------
__global__ __launch_bounds__(256) void merge_ln_kernel(
    const unsigned short* __restrict__ Opart, const float* __restrict__ lpart,
    const float* __restrict__ gamma, const float* __restrict__ beta,
    float* __restrict__ out)
{
    const int row  = blockIdx.x * 4 + (threadIdx.x >> 6);
    const int lane = threadIdx.x & 63;

    float linv = 1.0f / (lpart[row] + lpart[NROW + row]
                       + lpart[2 * NROW + row] + lpart[3 * NROW + row]);

    const unsigned short* o0 = Opart + (size_t)row * H_ + lane * 4;
    unsigned long long a0 = *(const unsigned long long*)o0;
    unsigned long long a1 = *(const unsigned long long*)(o0 + (size_t)NROW * H_);
    unsigned long long a2 = *(const unsigned long long*)(o0 + (size_t)2 * NROW * H_);
    unsigned long long a3 = *(const unsigned long long*)(o0 + (size_t)3 * NROW * H_);

    float vals[4];
    float sum = 0.0f;
    #pragma unroll
    for (int j = 0; j < 4; ++j) {
        vals[j] = (h2f((unsigned short)(a0 >> (16 * j)))
                 + h2f((unsigned short)(a1 >> (16 * j)))
                 + h2f((unsigned short)(a2 >> (16 * j)))
                 + h2f((unsigned short)(a3 >> (16 * j)))) * linv;
        sum += vals[j];
    }
    sum += __shfl_xor(sum, 1);  sum += __shfl_xor(sum, 2);
    sum += __shfl_xor(sum, 4);  sum += __shfl_xor(sum, 8);
    sum += __shfl_xor(sum, 16); sum += __shfl_xor(sum, 32);
    float mu = sum * (1.0f / H_);

    float sq = 0.0f;
    #pragma unroll
    for (int j = 0; j < 4; ++j) {
        float d = vals[j] - mu;
        sq += d * d;
    }
    sq += __shfl_xor(sq, 1);  sq += __shfl_xor(sq, 2);
    sq += __shfl_xor(sq, 4);  sq += __shfl_xor(sq, 8);
    sq += __shfl_xor(sq, 16); sq += __shfl_xor(sq, 32);
    float rstd = rsqrtf(sq * (1.0f / H_) + 1e-6f);

    f32x4 g  = *(const f32x4*)(gamma + lane * 4);
    f32x4 be = *(const f32x4*)(beta  + lane * 4);
    f32x4 o;
    #pragma unroll
    for (int j = 0; j < 4; ++j)
        o[j] = (vals[j] - mu) * rstd * g[j] + be[j];
    *(f32x4*)(out + (size_t)row * H_ + lane * 4) = o;
}

// ---------------------------------------------------------------------------
extern "C" void kernel_launch(void* const* d_in, const int* in_sizes, int n_in,
                              void* d_out, int out_size, void* d_ws, size_t ws_size,
                              hipStream_t stream)
{
    const float* query = (const float*)d_in[0];
    const float* key   = (const float*)d_in[1];
    const float* value = (const float*)d_in[2];
    const int*   mask  = (const int*)d_in[3];
    const float* Wq = (const float*)d_in[4];
    const float* bq = (const float*)d_in[5];
    const float* Wk = (const float*)d_in[6];
    const float* bk = (const float*)d_in[7];
    const float* Wv = (const float*)d_in[8];
    const float* bv = (const float*)d_in[9];
    const float* gamma = (const float*)d_in[10];
    const float* beta  = (const float*)d_in[11];
    float* out = (float*)d_out;

    const size_t NQK = (size_t)B_ * S_ * H_;             // 4.19M elem each
    unsigned short* pq = (unsigned short*)d_ws;          // frag-packed Q (fp16)
    unsigned short* pk = pq + NQK;                       // frag-packed K (fp16)
    unsigned short* pv = pk + NQK;                       // frag-packed V (fp16)
    unsigned short* wt = pv + NQK;                       // [3][256][96] fp16
    unsigned short* Op = wt + (size_t)3 * H_ * IN_;      // [4][NROW][256] fp16
    float*          lp = (float*)(Op + (size_t)4 * NROW * H_);  // [4][NROW] fp32
    unsigned long long* pm = (unsigned long long*)(lp + 4 * NROW); // [NROW][32] bits

    wconv_kernel<<<24, 256, 0, stream>>>(Wq, Wk, Wv, wt);
    maskpack_kernel<<<2048, 256, 0, stream>>>(mask, (unsigned*)pm);
    proj_kernel3<<<B_ * S_ / 16, 256, 0, stream>>>(query, key, value, wt,
                                                   bq, bk, bv, pq, pk, pv);
    attn_kernel<<<B_ * S_ / 32 * 4, 256, 0, stream>>>(pq, pk, pv, pm, Op, lp);
    merge_ln_kernel<<<NROW / 4, 256, 0, stream>>>(Op, lp, gamma, beta, out);
}

// Round 6
// 290.039 us; speedup vs baseline: 1.0920x; 1.0583x over previous
//
#include <hip/hip_runtime.h>

#define B_   8
#define S_   2048
#define IN_  96
#define H_   256
#define NROW (B_ * S_)          // 16384 rows

typedef float    f32x4 __attribute__((ext_vector_type(4)));
typedef _Float16 f16x8 __attribute__((ext_vector_type(8)));   // 8 fp16 in 4 VGPRs
typedef int      i32x4 __attribute__((ext_vector_type(4)));   // true 16B load

__device__ __forceinline__ unsigned short f2h(float x) {
    return __builtin_bit_cast(unsigned short, (_Float16)x);
}
__device__ __forceinline__ float h2f(unsigned short x) {
    return (float)__builtin_bit_cast(_Float16, x);
}
// LDS-only barrier: P-visibility needs lgkmcnt(0) only; vmem prefetches
// (K next chunk, packed-mask words, V) ride through instead of being
// drained by __syncthreads' vmcnt(0).
__device__ __forceinline__ void lds_barrier() {
    asm volatile("s_waitcnt lgkmcnt(0)\n\ts_barrier" ::: "memory");
}

// ---------------------------------------------------------------------------
// Kernel 0: convert W[96][256] fp32 -> wt[256][96] fp16 (transposed), x3 proj.
// ---------------------------------------------------------------------------
__global__ __launch_bounds__(256) void wconv_kernel(
    const float* __restrict__ Wq, const float* __restrict__ Wk,
    const float* __restrict__ Wv, unsigned short* __restrict__ wt)
{
    const int p  = blockIdx.x >> 3;
    const int h0 = (blockIdx.x & 7) * 32;
    const float* W = (p == 0) ? Wq : (p == 1) ? Wk : Wv;
    unsigned short* dst = wt + (size_t)p * H_ * IN_ + (size_t)h0 * IN_;

    __shared__ unsigned short lds[32][100];
    const int t = threadIdx.x;
    #pragma unroll
    for (int i = 0; i < 12; ++i) {
        int idx = i * 256 + t;
        int f = idx >> 5;
        int hl = idx & 31;
        lds[hl][f] = f2h(W[f * H_ + h0 + hl]);
    }
    __syncthreads();
    #pragma unroll
    for (int j = 0; j < 6; ++j) {
        int e = (j * 256 + t) * 2;
        int hl = e / IN_, f = e % IN_;
        unsigned int pk = (unsigned int)lds[hl][f] |
                          ((unsigned int)lds[hl][f + 1] << 16);
        ((unsigned int*)dst)[j * 256 + t] = pk;
    }
}

// ---------------------------------------------------------------------------
// Kernel 1: FUSED QKV projection + mask bit-pack.
//   bid%3==2 -> streaming packer block (line-exact 16B NT loads, the fast
//   round-3 packer; waves are pure-HBM and co-schedule with proj's MFMA/LDS
//   waves -> complementary pipes).  Other blocks: proj (round-0 form).
// ---------------------------------------------------------------------------
__global__ __launch_bounds__(256) void projmask_kernel(
    const float* __restrict__ query, const float* __restrict__ key,
    const float* __restrict__ value, const unsigned short* __restrict__ wt,
    const float* __restrict__ bq, const float* __restrict__ bk,
    const float* __restrict__ bv, const int* __restrict__ mask,
    unsigned short* __restrict__ pq, unsigned short* __restrict__ pk,
    unsigned short* __restrict__ pv, unsigned* __restrict__ pm32)
{
    __shared__ unsigned short Xs[3][16][104];     // proj: [p][r][f], pitch 104
    __shared__ unsigned char nib[4][8][64];       // packer: [wave][j][lane]

    const int bid = blockIdx.x;
    if ((bid % 3) == 2) {
        // ---- packer block: 4 waves x 8 rows (pairs) ----
        const int wave = threadIdx.x >> 6;
        const int lane = threadIdx.x & 63;
        const int wid  = (bid / 3) * 4 + wave;    // 0..2047
        #pragma unroll
        for (int rr = 0; rr < 4; ++rr) {
            const int r0 = wid * 8 + rr * 2;
            const int* m0 = mask + (size_t)r0 * S_ + lane * 4;
            const int* m1 = m0 + S_;
            i32x4 a[8], b[8];
            #pragma unroll
            for (int j = 0; j < 8; ++j)
                a[j] = __builtin_nontemporal_load((const i32x4*)(m0 + j * 256));
            #pragma unroll
            for (int j = 0; j < 8; ++j)
                b[j] = __builtin_nontemporal_load((const i32x4*)(m1 + j * 256));

            #pragma unroll
            for (int j = 0; j < 8; ++j) {
                unsigned n0 = (a[j][0] != 0 ? 1u : 0u) | (a[j][1] != 0 ? 2u : 0u)
                            | (a[j][2] != 0 ? 4u : 0u) | (a[j][3] != 0 ? 8u : 0u);
                unsigned n1 = (b[j][0] != 0 ? 1u : 0u) | (b[j][1] != 0 ? 2u : 0u)
                            | (b[j][2] != 0 ? 4u : 0u) | (b[j][3] != 0 ? 8u : 0u);
                nib[wave][j][lane] = (unsigned char)(n0 | (n1 << 4));
            }
            // same-wave LDS dependency only (DS ops in-order per wave)
            asm volatile("s_waitcnt lgkmcnt(0)" ::: "memory");

            unsigned long long v = *(const unsigned long long*)
                &nib[wave][lane >> 3][(lane & 7) * 8];
            unsigned long long x0 = v & 0x0F0F0F0F0F0F0F0FULL;
            unsigned long long x1 = (v >> 4) & 0x0F0F0F0F0F0F0F0FULL;
            x0 = (x0 | (x0 >> 4))  & 0x00FF00FF00FF00FFULL;
            x1 = (x1 | (x1 >> 4))  & 0x00FF00FF00FF00FFULL;
            x0 = (x0 | (x0 >> 8))  & 0x0000FFFF0000FFFFULL;
            x1 = (x1 | (x1 >> 8))  & 0x0000FFFF0000FFFFULL;
            x0 = (x0 | (x0 >> 16)) & 0xFFFFFFFFULL;
            x1 = (x1 | (x1 >> 16)) & 0xFFFFFFFFULL;

            pm32[(size_t)r0 * 64 + lane]       = (unsigned)x0;
            pm32[(size_t)(r0 + 1) * 64 + lane] = (unsigned)x1;
        }
        return;
    }
    const int bi = (bid / 3) * 2 + (bid % 3);     // proj tile id 0..1023

    const int t    = threadIdx.x;
    const int lane = t & 63;
    const int wave = t >> 6;
    const int col  = lane & 15;
    const int quad = lane >> 4;
    const int s0   = bi * 16;                     // flat row (b*S + sl)
    const int b    = s0 >> 11;
    const int sl   = s0 & (S_ - 1);

    const float* srcs[3] = { query + (size_t)s0 * IN_,
                             key   + (size_t)s0 * IN_,
                             value + (size_t)s0 * IN_ };
    #pragma unroll
    for (int p = 0; p < 3; ++p) {
        #pragma unroll
        for (int i = 0; i < 2; ++i) {
            int idx = i * 256 + t;                // float4 index, 384 total
            if (idx < 384) {
                f32x4 x = *(const f32x4*)(srcs[p] + idx * 4);
                int r = idx / 24;
                int f = (idx - r * 24) * 4;
                unsigned long long pkk =
                    (unsigned long long)f2h(x[0])
                  | ((unsigned long long)f2h(x[1]) << 16)
                  | ((unsigned long long)f2h(x[2]) << 32)
                  | ((unsigned long long)f2h(x[3]) << 48);
                *(unsigned long long*)&Xs[p][r][f] = pkk;
            }
        }
    }
    __syncthreads();

    const int hc = wave;
    #pragma unroll
    for (int p = 0; p < 3; ++p) {
        const unsigned short* wbase = wt + (size_t)p * H_ * IN_;
        f16x8 wfr[4][3];
        #pragma unroll
        for (int ht = 0; ht < 4; ++ht)
            #pragma unroll
            for (int kc = 0; kc < 3; ++kc)
                wfr[ht][kc] = *(const f16x8*)(wbase
                    + (size_t)(hc * 64 + ht * 16 + col) * IN_ + kc * 32 + quad * 8);
        f16x8 xfr[3];
        #pragma unroll
        for (int kc = 0; kc < 3; ++kc)
            xfr[kc] = *(const f16x8*)&Xs[p][col][kc * 32 + quad * 8];

        f32x4 acc[4];
        #pragma unroll
        for (int ht = 0; ht < 4; ++ht) acc[ht] = (f32x4)(0.0f);
        #pragma unroll
        for (int kc = 0; kc < 3; ++kc)
            #pragma unroll
            for (int ht = 0; ht < 4; ++ht)
                acc[ht] = (p < 2)
                    ? __builtin_amdgcn_mfma_f32_16x16x32_f16(xfr[kc], wfr[ht][kc], acc[ht], 0, 0, 0)
                    : __builtin_amdgcn_mfma_f32_16x16x32_f16(wfr[ht][kc], xfr[kc], acc[ht], 0, 0, 0);

        if (p < 2) {
            unsigned short* dst  = (p == 0) ? pq : pk;
            const float*    bias = (p == 0) ? bq : bk;
            #pragma unroll
            for (int ht = 0; ht < 4; ++ht) {
                float bh = bias[hc * 64 + ht * 16 + col];
                const int s    = hc * 2 + (ht >> 1);
                const int lq   = ((ht & 1) * 2 + (col >> 3)) * 16;
                const int j    = col & 7;
                #pragma unroll
                for (int r = 0; r < 4; ++r)
                    dst[(size_t)(((bi * 8 + s) * 64 + lq + quad * 4 + r)) * 8 + j]
                        = f2h(acc[ht][r] + bh);
            }
        } else {
            const int kl  = (sl & 63) + col;      // key within 64-chunk
            const int c   = sl >> 6;              // chunk within batch
            const int s2  = kl >> 5;
            const int qv  = (kl >> 3) & 3;
            const int jj  = col & 7;
            #pragma unroll
            for (int ht = 0; ht < 4; ++ht) {
                f32x4 b4 = *(const f32x4*)(bv + hc * 64 + ht * 16 + quad * 4);
                #pragma unroll
                for (int r = 0; r < 4; ++r)
                    pv[(size_t)(((b * 32 + c) * 32 + hc * 8 + ht * 2 + s2) * 64
                                + qv * 16 + quad * 4 + r) * 8 + jj]
                        = f2h(acc[ht][r] + b4[r]);
            }
        }
    }
}

// ---------------------------------------------------------------------------
// Kernel 2: flash attention, NO key split, rotated pipeline, FUSED final
// LayerNorm.  Each block owns 32 q-rows x all 2048 keys (32 chunks).  The
// full softmax denom and O live in-block, so the kernel applies 1/l and
// LayerNorm and writes the final fp32 output -- merge_ln kernel, Opart
// (33.5MB write + 50MB read) and lpart all eliminated.  Round-4 evidence:
// co-residency is weakly coupled to per-chunk wall, so grid 512 (2
// blocks/CU) costs little.
// ---------------------------------------------------------------------------
__global__ __launch_bounds__(256, 3) void attn_kernel(
    const unsigned short* __restrict__ pq, const unsigned short* __restrict__ pk,
    const unsigned short* __restrict__ pv, const unsigned long long* __restrict__ pm,
    const float* __restrict__ gamma, const float* __restrict__ beta,
    float* __restrict__ out)
{
    __shared__ __align__(16) unsigned short Qs[8448]; // Q frags / OT[32][264]
    __shared__ unsigned short P[2][32][68];       // [buf][q(2 strips)][k], pitch 68
    __shared__ float lsum[4][32];
    __shared__ float linv_s[32];

    const int tid  = threadIdx.x;
    const int wave = tid >> 6;
    const int lane = tid & 63;
    const int col  = lane & 15;
    const int quad = lane >> 4;

    const int b     = blockIdx.x & 7;             // batch == XCD (L2 locality)
    const int strip = blockIdx.x >> 3;            // 0..63 (32 rows each)
    const int q0    = strip << 5;

    // ---- stage Q fragments for both strips into LDS (one-time, 16 KB) ----
    {
        const unsigned short* qsrc = pq + (size_t)(b * 128 + strip * 2) * 4096;
        #pragma unroll
        for (int ph = 0; ph < 4; ++ph) {
            int i = ph * 2048 + tid * 8;
            *(f16x8*)&Qs[i] = *(const f16x8*)(qsrc + i);
        }
    }

    f32x4 O[2][4];                                // [strip][ht] 64-h slice
    #pragma unroll
    for (int st = 0; st < 2; ++st)
        #pragma unroll
        for (int ht = 0; ht < 4; ++ht) O[st][ht] = (f32x4)(0.0f);
    float l0 = 0.0f, l1 = 0.0f;

    const unsigned short* pkb = pk + (size_t)(b * 128) * 4096 + lane * 8;
    const unsigned short* pvb = pv + (size_t)(b * 32) * 32 * 512
                                   + (size_t)wave * 8 * 512 + lane * 8;

    // ---- packed-mask pointers: u32 word per (row, 32-key block) ----
    const unsigned* pm32 = (const unsigned*)pm;
    const int sh = (wave & 1) * 16 + quad * 4;    // bit offset within u32
    const unsigned* mp0 = pm32 + (size_t)(b * S_ + q0 + col) * 64 + (wave >> 1);
    const unsigned* mp1 = mp0 + 16 * 64;          // +16 rows

    // ---- K single buffer: load K(0) (tiles 0..3, one per wave) ----
    f16x8 kf[8];
    #pragma unroll
    for (int s = 0; s < 8; ++s)
        kf[s] = *(const f16x8*)(pkb + (size_t)wave * 4096 + s * 512);

    unsigned mc0 = mp0[0];                        // mask(0)
    unsigned mc1 = mp1[0];

    lds_barrier();                                // Q visible (no vmem drain)

    // ---- pipeline prologue: QK(0) -> sm(0) -> Pwrite(0, buf0) ----
    {
        f32x4 St0 = (f32x4)(0.0f), St1 = (f32x4)(0.0f);
        __builtin_amdgcn_s_setprio(1);
        #pragma unroll
        for (int s = 0; s < 8; ++s) {
            f16x8 q0f = *(const f16x8*)&Qs[s * 512 + lane * 8];
            f16x8 q1f = *(const f16x8*)&Qs[4096 + s * 512 + lane * 8];
            St0 = __builtin_amdgcn_mfma_f32_16x16x32_f16(kf[s], q0f, St0, 0, 0, 0);
            St1 = __builtin_amdgcn_mfma_f32_16x16x32_f16(kf[s], q1f, St1, 0, 0, 0);
        }
        __builtin_amdgcn_s_setprio(0);

        // K(1) reload
        {
            const unsigned short* kb = pkb + (size_t)(4 + wave) * 4096;
            #pragma unroll
            for (int s = 0; s < 8; ++s)
                kf[s] = *(const f16x8*)(kb + s * 512);
        }
        unsigned mn0 = mp0[2];                    // mask(1)
        unsigned mn1 = mp1[2];

        {
            unsigned bits = mc0 >> sh;
            unsigned long long pk64 = 0;
            #pragma unroll
            for (int r = 0; r < 4; ++r) {
                float e = exp2f(fmaf(St0[r], 0.0901679843f, -8.65617025f));
                float p = ((bits >> r) & 1u) ? e : 0.0f;
                _Float16 ph = (_Float16)p;
                l0 += (float)ph;
                pk64 |= (unsigned long long)__builtin_bit_cast(unsigned short, ph)
                        << (16 * r);
            }
            *(unsigned long long*)&P[0][col][wave * 16 + quad * 4] = pk64;
        }
        {
            unsigned bits = mc1 >> sh;
            unsigned long long pk64 = 0;
            #pragma unroll
            for (int r = 0; r < 4; ++r) {
                float e = exp2f(fmaf(St1[r], 0.0901679843f, -8.65617025f));
                float p = ((bits >> r) & 1u) ? e : 0.0f;
                _Float16 ph = (_Float16)p;
                l1 += (float)ph;
                pk64 |= (unsigned long long)__builtin_bit_cast(unsigned short, ph)
                        << (16 * r);
            }
            *(unsigned long long*)&P[0][16 + col][wave * 16 + quad * 4] = pk64;
        }
        mc0 = mn0; mc1 = mn1;

        lds_barrier();                            // P(0) visible
    }

    // ---- main loop: iter i computes QK(i+1) and PV(i), i = 0..30 ----
    #pragma unroll 2
    for (int i = 0; i < 31; ++i) {
        const int pb  = i & 1;
        const int cn2 = (i < 29) ? i + 2 : 31;    // K/mask prefetch, clamped

        // ---- V(i) loads (consumed at PV below, ~700cyc runway) ----
        const unsigned short* vb = pvb + (size_t)i * 32 * 512;
        f16x8 vf[4][2];
        #pragma unroll
        for (int ht = 0; ht < 4; ++ht)
            #pragma unroll
            for (int s2 = 0; s2 < 2; ++s2)
                vf[ht][s2] = *(const f16x8*)(vb + (size_t)(ht * 2 + s2) * 512);

        // ---- QK(i+1): kf holds K(i+1) ----
        f32x4 St0 = (f32x4)(0.0f), St1 = (f32x4)(0.0f);
        __builtin_amdgcn_s_setprio(1);
        #pragma unroll
        for (int s = 0; s < 8; ++s) {
            f16x8 q0f = *(const f16x8*)&Qs[s * 512 + lane * 8];
            f16x8 q1f = *(const f16x8*)&Qs[4096 + s * 512 + lane * 8];
            St0 = __builtin_amdgcn_mfma_f32_16x16x32_f16(kf[s], q0f, St0, 0, 0, 0);
            St1 = __builtin_amdgcn_mfma_f32_16x16x32_f16(kf[s], q1f, St1, 0, 0, 0);
        }
        __builtin_amdgcn_s_setprio(0);

        // ---- K(i+2) reload (consumed next iter; rides through barrier) ----
        {
            const unsigned short* kb = pkb + (size_t)(cn2 * 4 + wave) * 4096;
            #pragma unroll
            for (int s = 0; s < 8; ++s)
                kf[s] = *(const f16x8*)(kb + s * 512);
        }
        // ---- mask(i+2) prefetch (L2-resident, 4B) ----
        unsigned mn0 = mp0[cn2 * 2];
        unsigned mn1 = mp1[cn2 * 2];

        // ---- sm(i+1) -> Pwrite into buf pb^1 ----
        {
            unsigned bits = mc0 >> sh;
            unsigned long long pk64 = 0;
            #pragma unroll
            for (int r = 0; r < 4; ++r) {
                float e = exp2f(fmaf(St0[r], 0.0901679843f, -8.65617025f));
                float p = ((bits >> r) & 1u) ? e : 0.0f;
                _Float16 ph = (_Float16)p;
                l0 += (float)ph;
                pk64 |= (unsigned long long)__builtin_bit_cast(unsigned short, ph)
                        << (16 * r);
            }
            *(unsigned long long*)&P[pb ^ 1][col][wave * 16 + quad * 4] = pk64;
        }
        {
            unsigned bits = mc1 >> sh;
            unsigned long long pk64 = 0;
            #pragma unroll
            for (int r = 0; r < 4; ++r) {
                float e = exp2f(fmaf(St1[r], 0.0901679843f, -8.65617025f));
                float p = ((bits >> r) & 1u) ? e : 0.0f;
                _Float16 ph = (_Float16)p;
                l1 += (float)ph;
                pk64 |= (unsigned long long)__builtin_bit_cast(unsigned short, ph)
                        << (16 * r);
            }
            *(unsigned long long*)&P[pb ^ 1][16 + col][wave * 16 + quad * 4] = pk64;
        }
        mc0 = mn0; mc1 = mn1;

        // ---- PV(i) from P[pb] (visible since end of previous iter) ----
        __builtin_amdgcn_s_setprio(1);
        #pragma unroll
        for (int st = 0; st < 2; ++st) {
            #pragma unroll
            for (int s2 = 0; s2 < 2; ++s2) {
                union { unsigned long long u[2]; f16x8 v; } pu;
                const unsigned short* pr = &P[pb][st * 16 + col][s2 * 32 + quad * 8];
                pu.u[0] = *(const unsigned long long*)pr;
                pu.u[1] = *(const unsigned long long*)(pr + 4);
                f16x8 pf = pu.v;
                #pragma unroll
                for (int ht = 0; ht < 4; ++ht)
                    O[st][ht] = __builtin_amdgcn_mfma_f32_16x16x32_f16(pf, vf[ht][s2], O[st][ht], 0, 0, 0);
            }
        }
        __builtin_amdgcn_s_setprio(0);

        lds_barrier();                            // P(i+1) visible
    }

    // ---- pipeline epilogue: PV(31) from P[1] ----
    {
        const unsigned short* vb = pvb + (size_t)31 * 32 * 512;
        f16x8 vf[4][2];
        #pragma unroll
        for (int ht = 0; ht < 4; ++ht)
            #pragma unroll
            for (int s2 = 0; s2 < 2; ++s2)
                vf[ht][s2] = *(const f16x8*)(vb + (size_t)(ht * 2 + s2) * 512);
        __builtin_amdgcn_s_setprio(1);
        #pragma unroll
        for (int st = 0; st < 2; ++st) {
            #pragma unroll
            for (int s2 = 0; s2 < 2; ++s2) {
                union { unsigned long long u[2]; f16x8 v; } pu;
                const unsigned short* pr = &P[1][st * 16 + col][s2 * 32 + quad * 8];
                pu.u[0] = *(const unsigned long long*)pr;
                pu.u[1] = *(const unsigned long long*)(pr + 4);
                f16x8 pf = pu.v;
                #pragma unroll
                for (int ht = 0; ht < 4; ++ht)
                    O[st][ht] = __builtin_amdgcn_mfma_f32_16x16x32_f16(pf, vf[ht][s2], O[st][ht], 0, 0, 0);
            }
        }
        __builtin_amdgcn_s_setprio(0);
    }

    // ---- reduce l per strip: quads via shfl, waves via LDS ----
    l0 += __shfl_xor(l0, 16); l0 += __shfl_xor(l0, 32);
    l1 += __shfl_xor(l1, 16); l1 += __shfl_xor(l1, 32);
    if (lane < 16) { lsum[wave][lane] = l0; lsum[wave][16 + lane] = l1; }
    __syncthreads();                              // also: done reading Qs/P

    if (tid < 32) {
        float lt = lsum[0][tid] + lsum[1][tid] + lsum[2][tid] + lsum[3][tid];
        linv_s[tid] = 1.0f / lt;
    }

    // ---- O -> OT fp16 in LDS (reuse Qs; pitch 264 breaks bank aliasing) ----
    unsigned short* OT = Qs;
    #pragma unroll
    for (int st = 0; st < 2; ++st)
        #pragma unroll
        for (int ht = 0; ht < 4; ++ht)
            #pragma unroll
            for (int r = 0; r < 4; ++r)
                OT[(st * 16 + quad * 4 + r) * 264 + wave * 64 + ht * 16 + col]
                    = f2h(O[st][ht][r]);
    __syncthreads();

    // ---- fused 1/l + LayerNorm + fp32 output, one wave per row ----
    f32x4 g  = *(const f32x4*)(gamma + lane * 4);
    f32x4 be = *(const f32x4*)(beta  + lane * 4);
    #pragma unroll
    for (int p = 0; p < 8; ++p) {
        const int row = p * 4 + wave;             // 0..31
        float linv = linv_s[row];
        unsigned long long a =
            *(const unsigned long long*)&OT[row * 264 + lane * 4];
        float vals[4];
        float sum = 0.0f;
        #pragma unroll
        for (int j = 0; j < 4; ++j) {
            vals[j] = h2f((unsigned short)(a >> (16 * j))) * linv;
            sum += vals[j];
        }
        sum += __shfl_xor(sum, 1);  sum += __shfl_xor(sum, 2);
        sum += __shfl_xor(sum, 4);  sum += __shfl_xor(sum, 8);
        sum += __shfl_xor(sum, 16); sum += __shfl_xor(sum, 32);
        float mu = sum * (1.0f / H_);

        float sq = 0.0f;
        #pragma unroll
        for (int j = 0; j < 4; ++j) {
            float d = vals[j] - mu;
            sq += d * d;
        }
        sq += __shfl_xor(sq, 1);  sq += __shfl_xor(sq, 2);
        sq += __shfl_xor(sq, 4);  sq += __shfl_xor(sq, 8);
        sq += __shfl_xor(sq, 16); sq += __shfl_xor(sq, 32);
        float rstd = rsqrtf(sq * (1.0f / H_) + 1e-6f);

        f32x4 o;
        #pragma unroll
        for (int j = 0; j < 4; ++j)
            o[j] = (vals[j] - mu) * rstd * g[j] + be[j];
        *(f32x4*)(out + (size_t)(b * S_ + q0 + row) * H_ + lane * 4) = o;
    }
}

// ---------------------------------------------------------------------------
extern "C" void kernel_launch(void* const* d_in, const int* in_sizes, int n_in,
                              void* d_out, int out_size, void* d_ws, size_t ws_size,
                              hipStream_t stream)
{
    const float* query = (const float*)d_in[0];
    const float* key   = (const float*)d_in[1];
    const float* value = (const float*)d_in[2];
    const int*   mask  = (const int*)d_in[3];
    const float* Wq = (const float*)d_in[4];
    const float* bq = (const float*)d_in[5];
    const float* Wk = (const float*)d_in[6];
    const float* bk = (const float*)d_in[7];
    const float* Wv = (const float*)d_in[8];
    const float* bv = (const float*)d_in[9];
    const float* gamma = (const float*)d_in[10];
    const float* beta  = (const float*)d_in[11];
    float* out = (float*)d_out;

    const size_t NQK = (size_t)B_ * S_ * H_;             // 4.19M elem each
    unsigned short* pq = (unsigned short*)d_ws;          // frag-packed Q (fp16)
    unsigned short* pk = pq + NQK;                       // frag-packed K (fp16)
    unsigned short* pv = pk + NQK;                       // frag-packed V (fp16)
    unsigned short* wt = pv + NQK;                       // [3][256][96] fp16
    unsigned long long* pm = (unsigned long long*)
        (wt + (size_t)3 * H_ * IN_);                     // [NROW][32] bit-mask

    wconv_kernel<<<24, 256, 0, stream>>>(Wq, Wk, Wv, wt);
    projmask_kernel<<<1536, 256, 0, stream>>>(query, key, value, wt,
                                              bq, bk, bv, mask,
                                              pq, pk, pv, (unsigned*)pm);
    attn_kernel<<<512, 256, 0, stream>>>(pq, pk, pv, pm, gamma, beta, out);
}